// Round 2
// baseline (433.983 us; speedup 1.0000x reference)
//
#include <hip/hip_runtime.h>
#include <hip/hip_bf16.h>

#define B 16
#define C 1024
#define S 4096
#define R 64
#define NCCHUNK 16   // c-chunks in K1 (64 c each)
#define NSCHUNK 4    // s-chunks in K1 (1024 s each)

// ---------------- K1: cm partial sums --------------------------------------
// grid = B * NSCHUNK * NCCHUNK = 1024 blocks, 256 threads.
// Each block: fixed b, 1024 s (thread -> float4), 64 c, writes one partial.
__global__ __launch_bounds__(256) void k1_cm_partial(
    const float* __restrict__ x, const float* __restrict__ wm,
    float* __restrict__ cm_part) {
  int bid = blockIdx.x;
  int cchunk = bid & (NCCHUNK - 1);
  int schunk = (bid >> 4) & (NSCHUNK - 1);
  int b = bid >> 6;
  int s0 = schunk * 1024 + threadIdx.x * 4;
  const float* xp = x + ((size_t)b * C + (size_t)cchunk * 64) * S + s0;
  const float* wp = wm + cchunk * 64;
  float4 acc = {0.f, 0.f, 0.f, 0.f};
#pragma unroll 4
  for (int c = 0; c < 64; ++c) {
    float w = wp[c];
    float4 v = *(const float4*)(xp + (size_t)c * S);
    acc.x += w * v.x; acc.y += w * v.y; acc.z += w * v.z; acc.w += w * v.w;
  }
  *(float4*)(cm_part + ((size_t)cchunk * B + b) * S + s0) = acc;
}

// ---------------- K2: reduce partials, softmax exp + 1/Z -------------------
// grid = B blocks, 256 threads. (bm dropped: softmax is shift-invariant and
// the "whitened" mask is identically uniform, so bm cancels exactly.)
__global__ __launch_bounds__(256) void k2_softmax(
    const float* __restrict__ cm_part, float* __restrict__ e,
    float* __restrict__ zinv) {
  int b = blockIdx.x;
  float v[16];
#pragma unroll
  for (int j = 0; j < 16; ++j) {
    int s = threadIdx.x + j * 256;
    float acc = 0.f;
#pragma unroll
    for (int k = 0; k < NCCHUNK; ++k)
      acc += cm_part[((size_t)k * B + b) * S + s];
    v[j] = acc;
  }
  float m = -1e30f;
#pragma unroll
  for (int j = 0; j < 16; ++j) m = fmaxf(m, v[j]);
  for (int off = 32; off > 0; off >>= 1) m = fmaxf(m, __shfl_xor(m, off));
  __shared__ float redm[4], redz[4];
  int wid = threadIdx.x >> 6, lane = threadIdx.x & 63;
  if (lane == 0) redm[wid] = m;
  __syncthreads();
  m = fmaxf(fmaxf(redm[0], redm[1]), fmaxf(redm[2], redm[3]));
  float zs = 0.f, ev[16];
#pragma unroll
  for (int j = 0; j < 16; ++j) { ev[j] = expf(v[j] - m); zs += ev[j]; }
  for (int off = 32; off > 0; off >>= 1) zs += __shfl_xor(zs, off);
  if (lane == 0) redz[wid] = zs;
  __syncthreads();
  zs = redz[0] + redz[1] + redz[2] + redz[3];
#pragma unroll
  for (int j = 0; j < 16; ++j)
    e[(size_t)b * S + threadIdx.x + j * 256] = ev[j];
  if (threadIdx.x == 0) zinv[b] = 1.0f / zs;
}

// ---------------- K3: context = (1/S)*rowsum + zinv*<row, e> ---------------
// grid = B*C/4 = 4096 blocks, 256 threads (1 wave per (b,c) row).
__global__ __launch_bounds__(256) void k3_context(
    const float* __restrict__ x, const float* __restrict__ e,
    const float* __restrict__ zinv, float* __restrict__ context) {
  int row = blockIdx.x * 4 + (threadIdx.x >> 6);  // row = b*C + c
  int lane = threadIdx.x & 63;
  int b = row >> 10;
  const float* xp = x + (size_t)row * S;
  const float* ep = e + (size_t)b * S;
  float s1 = 0.f, s2 = 0.f;
#pragma unroll
  for (int i = 0; i < 16; ++i) {
    int idx = lane * 4 + i * 256;
    float4 xv = *(const float4*)(xp + idx);
    float4 evv = *(const float4*)(ep + idx);
    s1 += xv.x + xv.y + xv.z + xv.w;
    s2 += xv.x * evv.x + xv.y * evv.y + xv.z * evv.z + xv.w * evv.w;
  }
  for (int off = 32; off > 0; off >>= 1) {
    s1 += __shfl_down(s1, off);
    s2 += __shfl_down(s2, off);
  }
  if (lane == 0) context[row] = s1 * (1.0f / S) + s2 * zinv[b];
}

// ---------------- K4: MLP (fc1 -> LN -> ReLU -> fc2) -----------------------
// grid = B blocks, 256 threads.
__global__ __launch_bounds__(256) void k4_mlp(
    const float* __restrict__ context, const float* __restrict__ w1,
    const float* __restrict__ b1, const float* __restrict__ ln_g,
    const float* __restrict__ ln_b, const float* __restrict__ w2,
    const float* __restrict__ b2, float* __restrict__ out) {
  int b = blockIdx.x;
  __shared__ float ctx[C];
  __shared__ float tt[R];
  for (int j = threadIdx.x; j < C; j += 256) ctx[j] = context[b * C + j];
  __syncthreads();
  // t[r] = <context, w1[r,:]> + b1[r]; 4 threads per r.
  int r = threadIdx.x >> 2, q = threadIdx.x & 3;
  const float* w1p = w1 + (size_t)r * C + q * 256;
  const float* cp = ctx + q * 256;
  float part = 0.f;
#pragma unroll 4
  for (int i = 0; i < 256; ++i) part += cp[i] * w1p[i];
  part += __shfl_down(part, 1);
  part += __shfl_down(part, 2);
  if (q == 0) tt[r] = part + b1[r];
  __syncthreads();
  if (threadIdx.x < 64) {  // wave-uniform branch (wave 0)
    float v = tt[threadIdx.x];
    float mu = v;
    for (int off = 1; off < 64; off <<= 1) mu += __shfl_xor(mu, off);
    mu *= (1.0f / R);
    float d = v - mu;
    float var = d * d;
    for (int off = 1; off < 64; off <<= 1) var += __shfl_xor(var, off);
    var *= (1.0f / R);
    float t = d * rsqrtf(var + 1e-5f) * ln_g[threadIdx.x] + ln_b[threadIdx.x];
    tt[threadIdx.x] = fmaxf(t, 0.0f);
  }
  __syncthreads();
  for (int c = threadIdx.x; c < C; c += 256) {
    float acc = b2[c];
    const float* w2p = w2 + (size_t)c * R;
#pragma unroll
    for (int r2 = 0; r2 < R; ++r2) acc += tt[r2] * w2p[r2];
    out[b * C + c] = acc;
  }
}

extern "C" void kernel_launch(void* const* d_in, const int* in_sizes, int n_in,
                              void* d_out, int out_size, void* d_ws, size_t ws_size,
                              hipStream_t stream) {
  const float* x    = (const float*)d_in[0];
  const float* wm   = (const float*)d_in[1];
  // d_in[2] = bm: cancels exactly (softmax shift-invariance + zero whitened mask)
  const float* w1   = (const float*)d_in[3];
  const float* b1   = (const float*)d_in[4];
  const float* ln_g = (const float*)d_in[5];
  const float* ln_b = (const float*)d_in[6];
  const float* w2   = (const float*)d_in[7];
  const float* b2   = (const float*)d_in[8];
  float* out = (float*)d_out;

  float* ws = (float*)d_ws;
  float* cm_part = ws;                              // 16*16*4096 = 1,048,576 floats
  float* e       = cm_part + (size_t)NCCHUNK * B * S; // 65,536 floats
  float* zinv    = e + (size_t)B * S;               // 16 floats
  float* context = zinv + 64;                       // 16,384 floats

  k1_cm_partial<<<B * NSCHUNK * NCCHUNK, 256, 0, stream>>>(x, wm, cm_part);
  k2_softmax<<<B, 256, 0, stream>>>(cm_part, e, zinv);
  k3_context<<<B * C / 4, 256, 0, stream>>>(x, e, zinv, context);
  k4_mlp<<<B, 256, 0, stream>>>(context, w1, b1, ln_g, ln_b, w2, b2, out);
}

// Round 4
// 417.240 us; speedup vs baseline: 1.0401x; 1.0401x over previous
//
#include <hip/hip_runtime.h>
#include <hip/hip_bf16.h>

#define B 16
#define C 1024
#define S 4096
#define R 64
#define NCCHUNK 16   // c-chunks in K1 (64 c each)
#define NSCHUNK 4    // s-chunks in K1 (1024 s each)

typedef float f4 __attribute__((ext_vector_type(4)));

// ---------------- K1: cm partial sums --------------------------------------
// grid = B * NSCHUNK * NCCHUNK = 1024 blocks, 256 threads.
// Each block: fixed b, 1024 s (thread -> f4), 64 c, writes one partial row.
// Nontemporal x loads: x is streamed once here, once in K3 — no reuse.
__global__ __launch_bounds__(256) void k1_cm_partial(
    const float* __restrict__ x, const float* __restrict__ wm,
    float* __restrict__ cm_part) {
  int bid = blockIdx.x;
  int cchunk = bid & (NCCHUNK - 1);
  int schunk = (bid >> 4) & (NSCHUNK - 1);
  int b = bid >> 6;
  int s0 = schunk * 256 + threadIdx.x;  // in f4 units (S/4 = 1024 per row)
  const f4* xp = (const f4*)x + ((size_t)b * C + (size_t)cchunk * 64) * (S / 4) + s0;
  const float* wp = wm + cchunk * 64;
  f4 a0 = {0.f, 0.f, 0.f, 0.f}, a1 = {0.f, 0.f, 0.f, 0.f};
#pragma unroll 8
  for (int c = 0; c < 64; c += 2) {
    f4 v0 = __builtin_nontemporal_load(xp + (size_t)c * (S / 4));
    f4 v1 = __builtin_nontemporal_load(xp + (size_t)(c + 1) * (S / 4));
    a0 += wp[c] * v0;
    a1 += wp[c + 1] * v1;
  }
  ((f4*)cm_part)[((size_t)cchunk * B + b) * (S / 4) + s0] = a0 + a1;
}

// ---------------- K2: reduce partials + softmax exp + 1/Z ------------------
// grid = B blocks, 256 threads. f4 loads, 64 independent loads/thread.
// (bm dropped: softmax shift-invariance; whitened mask is exactly uniform.)
__global__ __launch_bounds__(256) void k2_softmax(
    const float* __restrict__ cm_part, float* __restrict__ e,
    float* __restrict__ zinv) {
  int b = blockIdx.x, tid = threadIdx.x;
  f4 v[4] = {{0.f,0.f,0.f,0.f},{0.f,0.f,0.f,0.f},{0.f,0.f,0.f,0.f},{0.f,0.f,0.f,0.f}};
#pragma unroll
  for (int k = 0; k < NCCHUNK; ++k) {
    const f4* cp = (const f4*)cm_part + ((size_t)k * B + b) * (S / 4);
#pragma unroll
    for (int j = 0; j < 4; ++j) v[j] += cp[tid + j * 256];
  }
  float m = -1e30f;
#pragma unroll
  for (int j = 0; j < 4; ++j)
    m = fmaxf(m, fmaxf(fmaxf(v[j][0], v[j][1]), fmaxf(v[j][2], v[j][3])));
  for (int off = 32; off > 0; off >>= 1) m = fmaxf(m, __shfl_xor(m, off));
  __shared__ float redm[4], redz[4];
  int wid = tid >> 6, lane = tid & 63;
  if (lane == 0) redm[wid] = m;
  __syncthreads();
  m = fmaxf(fmaxf(redm[0], redm[1]), fmaxf(redm[2], redm[3]));
  float zs = 0.f;
  f4 ev[4];
#pragma unroll
  for (int j = 0; j < 4; ++j) {
#pragma unroll
    for (int q = 0; q < 4; ++q) {
      float t = expf(v[j][q] - m);
      ev[j][q] = t;
      zs += t;
    }
  }
  for (int off = 32; off > 0; off >>= 1) zs += __shfl_xor(zs, off);
  if (lane == 0) redz[wid] = zs;
  __syncthreads();
  zs = redz[0] + redz[1] + redz[2] + redz[3];
  f4* ep = (f4*)(e + (size_t)b * S);
#pragma unroll
  for (int j = 0; j < 4; ++j) ep[tid + j * 256] = ev[j];
  if (tid == 0) zinv[b] = 1.0f / zs;
}

// ---------------- K3: context = (1/S)*rowsum + zinv*<row, e> ---------------
// grid = B*C/4 = 4096 blocks, 256 threads (1 wave per (b,c) row).
// Single combined shuffle chain; nontemporal x.
__global__ __launch_bounds__(256) void k3_context(
    const float* __restrict__ x, const float* __restrict__ e,
    const float* __restrict__ zinv, float* __restrict__ context) {
  int row = blockIdx.x * 4 + (threadIdx.x >> 6);  // row = b*C + c
  int lane = threadIdx.x & 63;
  int b = row >> 10;
  const f4* xp = (const f4*)(x + (size_t)row * S);
  const f4* ep = (const f4*)(e + (size_t)b * S);
  float zi = zinv[b];
  f4 s1 = {0.f, 0.f, 0.f, 0.f}, s2 = {0.f, 0.f, 0.f, 0.f};
#pragma unroll
  for (int i = 0; i < 16; ++i) {
    f4 xv = __builtin_nontemporal_load(xp + lane + i * 64);
    f4 evv = ep[lane + i * 64];
    s1 += xv;
    s2 += xv * evv;
  }
  float tot = (s1[0] + s1[1] + s1[2] + s1[3]) * (1.0f / S) +
              (s2[0] + s2[1] + s2[2] + s2[3]) * zi;
  for (int off = 32; off > 0; off >>= 1) tot += __shfl_down(tot, off);
  if (lane == 0) context[row] = tot;
}

// ---------------- K4: MLP (fc1 -> LN -> ReLU -> fc2) -----------------------
// grid = B blocks, 256 threads. fc1 coalesced: wave w owns r in [16w,16w+16),
// 64 lanes x f4 cover each 4 KB w1 row; context held in registers.
__global__ __launch_bounds__(256) void k4_mlp(
    const float* __restrict__ context, const float* __restrict__ w1,
    const float* __restrict__ b1, const float* __restrict__ ln_g,
    const float* __restrict__ ln_b, const float* __restrict__ w2,
    const float* __restrict__ b2, float* __restrict__ out) {
  int b = blockIdx.x;
  int tid = threadIdx.x, wid = tid >> 6, lane = tid & 63;
  __shared__ float tt[R];
  const f4* ctxp = (const f4*)(context + (size_t)b * C);
  f4 c0 = ctxp[lane], c1 = ctxp[lane + 64], c2 = ctxp[lane + 128], c3 = ctxp[lane + 192];
#pragma unroll
  for (int i = 0; i < 16; ++i) {
    int r = wid * 16 + i;
    const f4* wp = (const f4*)(w1 + (size_t)r * C);
    f4 p = c0 * wp[lane] + c1 * wp[lane + 64] + c2 * wp[lane + 128] + c3 * wp[lane + 192];
    float dot = p[0] + p[1] + p[2] + p[3];
#pragma unroll
    for (int off = 32; off > 0; off >>= 1) dot += __shfl_xor(dot, off);
    if (lane == 0) tt[r] = dot + b1[r];
  }
  __syncthreads();
  if (tid < 64) {  // wave-uniform branch (wave 0): LayerNorm + ReLU over R=64
    float v = tt[tid];
    float mu = v;
    for (int off = 1; off < 64; off <<= 1) mu += __shfl_xor(mu, off);
    mu *= (1.0f / R);
    float d = v - mu;
    float var = d * d;
    for (int off = 1; off < 64; off <<= 1) var += __shfl_xor(var, off);
    var *= (1.0f / R);
    tt[tid] = fmaxf(d * rsqrtf(var + 1e-5f) * ln_g[tid] + ln_b[tid], 0.0f);
  }
  __syncthreads();
  f4 t4[16];
#pragma unroll
  for (int k = 0; k < 16; ++k) t4[k] = *(const f4*)(tt + k * 4);
#pragma unroll
  for (int cc = 0; cc < 4; ++cc) {
    int c = tid + cc * 256;
    const f4* w2p = (const f4*)(w2 + (size_t)c * R);
    f4 acc = {0.f, 0.f, 0.f, 0.f};
#pragma unroll
    for (int k = 0; k < 16; ++k) acc += w2p[k] * t4[k];
    out[(size_t)b * C + c] = acc[0] + acc[1] + acc[2] + acc[3] + b2[c];
  }
}

extern "C" void kernel_launch(void* const* d_in, const int* in_sizes, int n_in,
                              void* d_out, int out_size, void* d_ws, size_t ws_size,
                              hipStream_t stream) {
  const float* x    = (const float*)d_in[0];
  const float* wm   = (const float*)d_in[1];
  // d_in[2] = bm: cancels exactly (softmax shift-invariance + zero whitened mask)
  const float* w1   = (const float*)d_in[3];
  const float* b1   = (const float*)d_in[4];
  const float* ln_g = (const float*)d_in[5];
  const float* ln_b = (const float*)d_in[6];
  const float* w2   = (const float*)d_in[7];
  const float* b2   = (const float*)d_in[8];
  float* out = (float*)d_out;

  float* ws = (float*)d_ws;
  float* cm_part = ws;                                // 16*16*4096 = 1,048,576 floats
  float* e       = cm_part + (size_t)NCCHUNK * B * S; // 65,536 floats
  float* zinv    = e + (size_t)B * S;                 // 16 floats
  float* context = zinv + 64;                         // 16,384 floats

  k1_cm_partial<<<B * NSCHUNK * NCCHUNK, 256, 0, stream>>>(x, wm, cm_part);
  k2_softmax<<<B, 256, 0, stream>>>(cm_part, e, zinv);
  k3_context<<<B * C / 4, 256, 0, stream>>>(x, e, zinv, context);
  k4_mlp<<<B, 256, 0, stream>>>(context, w1, b1, ln_g, ln_b, w2, b2, out);
}